// Round 3
// baseline (1512158.887 us; speedup 1.0000x reference)
//
#include <hip/hip_runtime.h>
#include <math.h>

#define TT 1024
#define BB 128
#define HH 256

__device__ __forceinline__ float sigm(float x) { return 1.0f / (1.0f + expf(-x)); }

// One persistent WG per (group, hidden-slice). Group = 16 WGs covering all 256
// hidden units for C16 = CHUNKS*16 chains. Weights live in LDS for the whole
// layer; h is exchanged between the 16 WGs of a group via double-buffered
// global hbuf + per-group arrival counter (one counter per 128B line).
//
// Barrier protocol v2 (round 2): fully memory-side h exchange.
//  - h stores:  __hip_atomic_store RELAXED/AGENT  -> SC1, bypasses the
//    non-coherent per-XCD L2, completes at the memory-side coherent point.
//  - h loads:   __hip_atomic_load  RELAXED/AGENT  -> SC1, reads the coherent
//    point directly; CANNOT see stale L1/L2 lines.
//  - publish:   __syncthreads() drains each wave's vmcnt (h stores globally
//    visible), then a RELAXED memory-side fetch_add bumps the counter.
//  - poll:      RELAXED fetch_add(0) (memory-side RMW, always fresh).
//  => NO buffer_wbl2 on the writer, NO buffer_inv on the readers. The old
//     protocol walked the full 4MiB L2 tag array (wbl2) and invalidated all
//     of L1+L2 (inv) once per step per WG - pure cache-maintenance overhead
//     on the 1792-step critical path. W/X lines now stay warm across steps;
//     Y stays cached-dirty and is flushed once by the end-of-kernel release.
template <int CHUNKS, int NSLX>
__global__ __launch_bounds__(256, 1) void lstm_layer(
    const float* __restrict__ X, float* __restrict__ Y,
    const float* __restrict__ Wih, const float* __restrict__ Whh,
    const float* __restrict__ bih, const float* __restrict__ bhh,
    float* __restrict__ hbuf, unsigned int* __restrict__ ctr,
    int n_steps, int rate, size_t HB) {
  constexpr int Din = NSLX * 128;
  constexpr int Dtot = Din + HH;
  constexpr int C16 = CHUNKS * 16;

  extern __shared__ float lds[];
  float* Wl = lds;             // [Dtot][64]  (d slow; 64 = 16 units x 4 gates fast)
  float* xh = lds + Dtot * 64; // [C16][132]  staging, padded pitch

  const int tid = threadIdx.x;
  const int jj = tid & 15;   // hidden unit within slice
  const int ccl = tid >> 4;  // chain within 16-chunk
  const int group = blockIdx.x >> 4;
  const int slice = blockIdx.x & 15;
  const int unit = slice * 16 + jj;
  unsigned int* const myctr = ctr + (group << 5); // 128B-padded counter

  // One-time: load this WG's 64 fused weight rows into LDS, transposed to [d][rr].
  for (int idx = tid; idx < Dtot * 64; idx += 256) {
    int d = idx >> 6, rr = idx & 63;
    int grow = ((rr & 3) << 8) + slice * 16 + (rr >> 2); // gate*256 + unit
    Wl[idx] = (d < Din) ? Wih[(size_t)grow * Din + d]
                        : Whh[(size_t)grow * HH + (d - Din)];
  }
  float bsum[4];
#pragma unroll
  for (int g = 0; g < 4; ++g)
    bsum[g] = bih[(g << 8) + unit] + bhh[(g << 8) + unit];

  float creg[CHUNKS];
#pragma unroll
  for (int ch = 0; ch < CHUNKS; ++ch) creg[ch] = 0.f;

  __syncthreads();

  const int q00 = group * C16; // first global chain of this group
  const int toff = q00 >> 7;   // time offset (uniform per group; 16/32-aligned
                               // chain blocks never cross a 128 boundary)
  const int scc = tid >> 4;         // staging row within 16
  const int sd = (tid & 15) << 3;   // staging column (8 floats)
  bool dead = false;

  float acc[CHUNKS][4];

  for (int s = 0; s < n_steps; ++s) {
    float* hwrite = hbuf + (size_t)(s & 1) * HB;
    const float* hread = hbuf + (size_t)((s & 1) ^ 1) * HB;
    const int t = s * rate + toff;

#pragma unroll
    for (int ch = 0; ch < CHUNKS; ++ch)
#pragma unroll
      for (int g = 0; g < 4; ++g) acc[ch][g] = 0.f;

    // GEMM over one staged 128-d slice; W reads shared across chunks.
    auto gemm_slice = [&](const float* Wbase) {
      const float4* W4 = ((const float4*)Wbase) + jj;
      const float4* xh4 = (const float4*)xh;
#pragma unroll
      for (int d4 = 0; d4 < 32; ++d4) {
        float4 w0 = W4[(d4 * 4 + 0) * 16];
        float4 w1 = W4[(d4 * 4 + 1) * 16];
        float4 w2 = W4[(d4 * 4 + 2) * 16];
        float4 w3 = W4[(d4 * 4 + 3) * 16];
#pragma unroll
        for (int ch = 0; ch < CHUNKS; ++ch) {
          float4 xv = xh4[(ch * 16 + ccl) * 33 + d4];
          acc[ch][0] += xv.x * w0.x + xv.y * w1.x + xv.z * w2.x + xv.w * w3.x;
          acc[ch][1] += xv.x * w0.y + xv.y * w1.y + xv.z * w2.y + xv.w * w3.y;
          acc[ch][2] += xv.x * w0.z + xv.y * w1.z + xv.z * w2.z + xv.w * w3.z;
          acc[ch][3] += xv.x * w0.w + xv.y * w1.w + xv.z * w2.w + xv.w * w3.w;
        }
      }
    };

    // ---- x contribution: no cross-WG dependency, overlaps barrier wait ----
#pragma unroll
    for (int dsl = 0; dsl < NSLX; ++dsl) {
      __syncthreads();
#pragma unroll
      for (int ch = 0; ch < CHUNKS; ++ch) {
        const int q = q00 + (ch << 4) + scc;
        const float* src = X + ((size_t)t * BB + (q & 127)) * Din + (dsl << 7) + sd;
        *(float4*)&xh[(ch * 16 + scc) * 132 + sd] = *(const float4*)src;
        *(float4*)&xh[(ch * 16 + scc) * 132 + sd + 4] = *(const float4*)(src + 4);
      }
      __syncthreads();
      gemm_slice(Wl + (size_t)(dsl << 7) * 64);
    }

    // ---- wait until all 16 WGs of the group published h(s-1) ----
    if (s > 0) {
      if (tid == 0 && !dead) {
        const unsigned int target = 16u * (unsigned int)s;
        int spins = 0;
        for (;;) {
          // RELAXED RMW poll: memory-side (always fresh), no fence traffic.
          unsigned int v = __hip_atomic_fetch_add(myctr, 0u, __ATOMIC_RELAXED,
                                                  __HIP_MEMORY_SCOPE_AGENT);
          if (v >= target) break;
          __builtin_amdgcn_s_sleep(2);
          if (++spins > (1 << 18)) { dead = true; break; } // never hang the bench
        }
      }
      __syncthreads();
      // NO acquire fence: h loads below are agent-scope (SC1) and read the
      // memory-side coherent point directly - stale caches are bypassed.
    }

    // ---- h contribution (agent-scope scalar loads, bypass L1/L2) ----
#pragma unroll
    for (int dsl = 0; dsl < 2; ++dsl) {
      __syncthreads();
#pragma unroll
      for (int ch = 0; ch < CHUNKS; ++ch) {
        const int q = q00 + (ch << 4) + scc;
        const float* src = hread + (size_t)q * HH + (dsl << 7) + sd;
        float* dst = &xh[(ch * 16 + scc) * 132 + sd];
#pragma unroll
        for (int u = 0; u < 8; ++u)
          dst[u] = __hip_atomic_load(src + u, __ATOMIC_RELAXED,
                                     __HIP_MEMORY_SCOPE_AGENT);
      }
      __syncthreads();
      gemm_slice(Wl + (size_t)(Din + (dsl << 7)) * 64);
    }

    // ---- LSTM pointwise + writes ----
#pragma unroll
    for (int ch = 0; ch < CHUNKS; ++ch) {
      const int q = q00 + (ch << 4) + ccl;
      const int b = q & 127;
      float gi = sigm(acc[ch][0] + bsum[0]);
      float gf = sigm(acc[ch][1] + bsum[1]);
      float gg = tanhf(acc[ch][2] + bsum[2]);
      float go = sigm(acc[ch][3] + bsum[3]);
      float c = gf * creg[ch] + gi * gg;
      creg[ch] = c;
      float h = go * tanhf(c);
      // h: agent-scope store -> completes at the memory-side coherent point.
      __hip_atomic_store(&hwrite[(size_t)q * HH + unit], h, __ATOMIC_RELAXED,
                         __HIP_MEMORY_SCOPE_AGENT);
      Y[((size_t)t * BB + b) * HH + unit] = h; // normal cached store
    }

    // ---- publish h(s): syncthreads drains each wave's vmcnt (SC1 stores are
    //      then globally visible); RELAXED memory-side RMW bumps the counter.
    //      No wbl2, no inv - zero cache-maintenance on the critical path.
    __syncthreads();
    if (tid == 0)
      __hip_atomic_fetch_add(myctr, 1u, __ATOMIC_RELAXED,
                             __HIP_MEMORY_SCOPE_AGENT);
  }
}

__global__ void zero_out(float* p, size_t n) {
  size_t i = (size_t)blockIdx.x * blockDim.x + threadIdx.x;
  if (i < n) p[i] = 0.f;
}

template <int C, int N>
static void launch_layer(dim3 grid, size_t lds, hipStream_t stream,
                         const float* X, float* Y, const float* Wih,
                         const float* Whh, const float* bih, const float* bhh,
                         float* hbuf, unsigned int* ctr, int n_steps, int rate,
                         size_t HB) {
  hipFuncSetAttribute(reinterpret_cast<const void*>(&lstm_layer<C, N>),
                      hipFuncAttributeMaxDynamicSharedMemorySize, (int)lds);
  lstm_layer<C, N><<<grid, dim3(256), lds, stream>>>(
      X, Y, Wih, Whh, bih, bhh, hbuf, ctr, n_steps, rate, HB);
}

extern "C" void kernel_launch(void* const* d_in, const int* in_sizes, int n_in,
                              void* d_out, int out_size, void* d_ws, size_t ws_size,
                              hipStream_t stream) {
  const float* x = (const float*)d_in[0];
  const float* Wih0 = (const float*)d_in[1];
  const float* Whh0 = (const float*)d_in[2];
  const float* bih0 = (const float*)d_in[3];
  const float* bhh0 = (const float*)d_in[4];
  const float* Wih1 = (const float*)d_in[5];
  const float* Whh1 = (const float*)d_in[6];
  const float* bih1 = (const float*)d_in[7];
  const float* bhh1 = (const float*)d_in[8];
  const float* Wih2 = (const float*)d_in[9];
  const float* Whh2 = (const float*)d_in[10];
  const float* bih2 = (const float*)d_in[11];
  const float* bhh2 = (const float*)d_in[12];

  const size_t outElems = (size_t)TT * BB * HH; // 33,554,432
  // hbuf + 16 groups x 32-uint (128B) padded counters
  const size_t hcBytes = (size_t)2 * 512 * HH * sizeof(float) + 16 * 128;
  const size_t needWs = outElems * sizeof(float) + hcBytes;

  // Workspace guard: convert a potential OOB-write container-kill into a
  // clean verification failure (diagnostic signal, never a crash).
  if (ws_size < needWs) {
    zero_out<<<dim3((unsigned)((outElems + 255) / 256)), dim3(256), 0, stream>>>(
        (float*)d_out, outElems);
    return;
  }

  float* out0 = (float*)d_ws;                   // 134 MB scratch output
  float* hbuf = (float*)((char*)d_ws + outElems * sizeof(float)); // 1 MB
  unsigned int* ctr =
      (unsigned int*)((char*)hbuf + (size_t)2 * 512 * HH * sizeof(float));
  float* dout = (float*)d_out;

  // LDS: Wl = Dtot*64 floats, xh = CHUNKS*16*132 floats
  const size_t lds0 = (384 * 64 + 16 * 132) * sizeof(float);  // 106,752
  const size_t lds12 = (512 * 64 + 32 * 132) * sizeof(float); // 147,968

  // Layer 0: rate 1, Beff 128, Din 128 -> 8 groups x 16 WGs = 128
  hipMemsetAsync(hbuf, 0, hcBytes, stream);
  launch_layer<1, 1>(dim3(128), lds0, stream, x, out0, Wih0, Whh0, bih0, bhh0,
                     hbuf, ctr, 1024, 1, (size_t)128 * HH);

  // Layer 1: rate 2, Beff 256, Din 256 -> 8 groups x 16 WGs = 128, CHUNKS=2
  hipMemsetAsync(hbuf, 0, hcBytes, stream);
  launch_layer<2, 2>(dim3(128), lds12, stream, out0, dout, Wih1, Whh1, bih1,
                     bhh1, hbuf, ctr, 512, 2, (size_t)256 * HH);

  // Layer 2: rate 4, Beff 512, Din 256 -> 16 groups x 16 WGs = 256, CHUNKS=2
  hipMemsetAsync(hbuf, 0, hcBytes, stream);
  launch_layer<2, 2>(dim3(256), lds12, stream, dout, out0, Wih2, Whh2, bih2,
                     bhh2, hbuf, ctr, 256, 4, (size_t)512 * HH);

  // final result back to d_out
  hipMemcpyAsync(d_out, out0, outElems * sizeof(float), hipMemcpyDeviceToDevice,
                 stream);
}

// Round 4
// 457285.596 us; speedup vs baseline: 3.3068x; 3.3068x over previous
//
#include <hip/hip_runtime.h>
#include <math.h>

#define TT 1024
#define BB 128
#define HH 256

__device__ __forceinline__ float sigm(float x) { return 1.0f / (1.0f + expf(-x)); }

// ---------------------------------------------------------------------------
// K-split kernel (layers 0 and 1): 32 WGs per group, 8 hidden units per WG,
// 4-way K-split across threads with shfl_xor butterfly combine.
//   thread = ccl(3b) | kh(2b) | jj(3b):  jj = unit 0-7, kh = K quarter,
//   ccl = chain octant (CH_T = C16/8 chains per thread).
// Per thread per step: CH_T x 4-gate outputs, each reduced over Dtot/4 dims,
// then acc += shfl_xor(acc,8); acc += shfl_xor(acc,16) completes the sum in
// all 4 kh replicas (identical pointwise; only kh==0 stores h/Y).
// LDS: Wl[Dtot][32] (gate-vector float4 per unit) + xh[C16][264] staging.
// Sync protocol = round-2 proven: RELAXED RMW poll, RELEASE fetch_add publish
// (one wbl2), one agent ACQUIRE fence in all waves after the poll.
// ---------------------------------------------------------------------------
template <int C16, int DinT>
__global__ __launch_bounds__(256, 1) void lstm_layer_ks(
    const float* __restrict__ X, float* __restrict__ Y,
    const float* __restrict__ Wih, const float* __restrict__ Whh,
    const float* __restrict__ bih, const float* __restrict__ bhh,
    float* __restrict__ hbuf, unsigned int* __restrict__ ctr,
    int n_steps, int rate, size_t HB) {
  constexpr int Dtot = DinT + HH;
  constexpr int CH_T = C16 / 8;       // chains per thread
  constexpr int PITCH = 264;          // xh row pitch in floats (66 f4)

  extern __shared__ float lds[];
  float* Wl = lds;                    // [Dtot][32]  (d slow; 32 = 8 units x 4 gates)
  float* xh = lds + Dtot * 32;        // [C16][264]

  const int tid = threadIdx.x;
  const int jj = tid & 7;             // unit within slice
  const int kh = (tid >> 3) & 3;      // K quarter
  const int ccl = tid >> 5;           // chain octant (0-7)
  const int group = blockIdx.x >> 5;  // 32 WGs per group
  const int slice = blockIdx.x & 31;
  const int unit = slice * 8 + jj;
  unsigned int* const myctr = ctr + (group << 5);

  // One-time: Wl[d][u*4+g] = fused weight row (gate-vector layout).
  for (int idx = tid; idx < Dtot * 32; idx += 256) {
    int d = idx >> 5, col = idx & 31;
    int grow = ((col & 3) << 8) + slice * 8 + (col >> 2); // gate*256 + unit
    Wl[idx] = (d < DinT) ? Wih[(size_t)grow * DinT + d]
                         : Whh[(size_t)grow * HH + (d - DinT)];
  }
  float bsum[4];
#pragma unroll
  for (int g = 0; g < 4; ++g)
    bsum[g] = bih[(g << 8) + unit] + bhh[(g << 8) + unit];

  float creg[CH_T];
#pragma unroll
  for (int c = 0; c < CH_T; ++c) creg[c] = 0.f;

  __syncthreads();

  const int q00 = group * C16;   // first global chain (C16-aligned; never
  const int toff = q00 >> 7;     // crosses a 128 boundary -> uniform toff)
  bool dead = false;

  float acc[CH_T][4];

  for (int s = 0; s < n_steps; ++s) {
    float* hwrite = hbuf + (size_t)(s & 1) * HB;
    const float* hread = hbuf + (size_t)((s & 1) ^ 1) * HB;
    const int t = s * rate + toff;

#pragma unroll
    for (int c = 0; c < CH_T; ++c)
#pragma unroll
      for (int g = 0; g < 4; ++g) acc[c][g] = 0.f;

    // GEMM over this thread's K-quarter of one staged operand block.
    // wb = Wl row offset (0 for x, DinT for h); NI = d4 iterations (Kq/4).
    auto gemm_q = [&](int wb, int ko, int ko4, int NI) {
      const float4* W4 = (const float4*)Wl;
      const float4* X4 = (const float4*)xh;
      for (int d4 = 0; d4 < NI; ++d4) {
        float4 w0 = W4[(wb + ko + d4 * 4 + 0) * 8 + jj];
        float4 w1 = W4[(wb + ko + d4 * 4 + 1) * 8 + jj];
        float4 w2 = W4[(wb + ko + d4 * 4 + 2) * 8 + jj];
        float4 w3 = W4[(wb + ko + d4 * 4 + 3) * 8 + jj];
#pragma unroll
        for (int c = 0; c < CH_T; ++c) {
          float4 xv = X4[(ccl * CH_T + c) * 66 + ko4 + d4];
          acc[c][0] += xv.x * w0.x + xv.y * w1.x + xv.z * w2.x + xv.w * w3.x;
          acc[c][1] += xv.x * w0.y + xv.y * w1.y + xv.z * w2.y + xv.w * w3.y;
          acc[c][2] += xv.x * w0.z + xv.y * w1.z + xv.z * w2.z + xv.w * w3.z;
          acc[c][3] += xv.x * w0.w + xv.y * w1.w + xv.z * w2.w + xv.w * w3.w;
        }
      }
    };

    // ---- x contribution (no cross-WG dependency; overlaps peers' publish) --
    // stage all C16 x Din floats, one sync pair, gemm the kh quarter.
#pragma unroll
    for (int idx = tid; idx < C16 * (DinT / 4); idx += 256) {
      int r = idx / (DinT / 4), cl = idx % (DinT / 4);
      int q = q00 + r;
      *(float4*)&xh[r * PITCH + cl * 4] =
          *(const float4*)(X + ((size_t)t * BB + (q & 127)) * DinT + cl * 4);
    }
    __syncthreads();
    gemm_q(0, kh * (DinT / 4), kh * (DinT / 16), DinT / 16);

    // ---- wait until all 32 WGs of the group published h(s-1) ----
    if (s > 0) {
      if (tid == 0 && !dead) {
        const unsigned int target = 32u * (unsigned int)s;
        int spins = 0;
        for (;;) {
          unsigned int v = __hip_atomic_fetch_add(myctr, 0u, __ATOMIC_RELAXED,
                                                  __HIP_MEMORY_SCOPE_AGENT);
          if (v >= target) break;
          __builtin_amdgcn_s_sleep(2);
          if (++spins > (1 << 18)) { dead = true; break; }
        }
      }
      __syncthreads();  // also guards xh reuse (gemm_x done in all threads)
      __builtin_amdgcn_fence(__ATOMIC_ACQUIRE, "agent");
    } else {
      __syncthreads();
    }

    // ---- h contribution: stage all C16 x 256, one sync, gemm kh quarter ----
#pragma unroll
    for (int idx = tid; idx < C16 * 64; idx += 256) {
      int r = idx >> 6, cl = idx & 63;
      int q = q00 + r;
      *(float4*)&xh[r * PITCH + cl * 4] =
          *(const float4*)(hread + (size_t)q * HH + cl * 4);
    }
    __syncthreads();
    gemm_q(DinT, kh * 64, kh * 16, 16);

    // ---- butterfly combine across the 4 kh replicas (lane bits 3,4) ----
#pragma unroll
    for (int c = 0; c < CH_T; ++c)
#pragma unroll
      for (int g = 0; g < 4; ++g) {
        float v = acc[c][g];
        v += __shfl_xor(v, 8);
        v += __shfl_xor(v, 16);
        acc[c][g] = v;
      }

    // ---- LSTM pointwise (all kh replicas, identical); stores kh==0 only ----
#pragma unroll
    for (int c = 0; c < CH_T; ++c) {
      const int q = q00 + ccl * CH_T + c;
      const int b = q & 127;
      float gi = sigm(acc[c][0] + bsum[0]);
      float gf = sigm(acc[c][1] + bsum[1]);
      float gg = tanhf(acc[c][2] + bsum[2]);
      float go = sigm(acc[c][3] + bsum[3]);
      float cc = gf * creg[c] + gi * gg;
      creg[c] = cc;
      float h = go * tanhf(cc);
      if (kh == 0) {
        hwrite[(size_t)q * HH + unit] = h;
        Y[((size_t)t * BB + b) * HH + unit] = h;
      }
    }

    // ---- publish: sync drains vmcnt; RELEASE RMW does one wbl2 + bump ----
    __syncthreads();
    if (tid == 0)
      __hip_atomic_fetch_add(myctr, 1u, __ATOMIC_RELEASE,
                             __HIP_MEMORY_SCOPE_AGENT);
  }
}

// ---------------------------------------------------------------------------
// Round-2 proven kernel, used for layer 2 (8-unit split would need 512 WGs).
// ---------------------------------------------------------------------------
template <int CHUNKS, int NSLX>
__global__ __launch_bounds__(256, 1) void lstm_layer(
    const float* __restrict__ X, float* __restrict__ Y,
    const float* __restrict__ Wih, const float* __restrict__ Whh,
    const float* __restrict__ bih, const float* __restrict__ bhh,
    float* __restrict__ hbuf, unsigned int* __restrict__ ctr,
    int n_steps, int rate, size_t HB) {
  constexpr int Din = NSLX * 128;
  constexpr int Dtot = Din + HH;
  constexpr int C16 = CHUNKS * 16;

  extern __shared__ float lds[];
  float* Wl = lds;
  float* xh = lds + Dtot * 64;

  const int tid = threadIdx.x;
  const int jj = tid & 15;
  const int ccl = tid >> 4;
  const int group = blockIdx.x >> 4;
  const int slice = blockIdx.x & 15;
  const int unit = slice * 16 + jj;
  unsigned int* const myctr = ctr + (group << 5);

  for (int idx = tid; idx < Dtot * 64; idx += 256) {
    int d = idx >> 6, rr = idx & 63;
    int grow = ((rr & 3) << 8) + slice * 16 + (rr >> 2);
    Wl[idx] = (d < Din) ? Wih[(size_t)grow * Din + d]
                        : Whh[(size_t)grow * HH + (d - Din)];
  }
  float bsum[4];
#pragma unroll
  for (int g = 0; g < 4; ++g)
    bsum[g] = bih[(g << 8) + unit] + bhh[(g << 8) + unit];

  float creg[CHUNKS];
#pragma unroll
  for (int ch = 0; ch < CHUNKS; ++ch) creg[ch] = 0.f;

  __syncthreads();

  const int q00 = group * C16;
  const int toff = q00 >> 7;
  const int scc = tid >> 4;
  const int sd = (tid & 15) << 3;
  bool dead = false;

  float acc[CHUNKS][4];

  for (int s = 0; s < n_steps; ++s) {
    float* hwrite = hbuf + (size_t)(s & 1) * HB;
    const float* hread = hbuf + (size_t)((s & 1) ^ 1) * HB;
    const int t = s * rate + toff;

#pragma unroll
    for (int ch = 0; ch < CHUNKS; ++ch)
#pragma unroll
      for (int g = 0; g < 4; ++g) acc[ch][g] = 0.f;

    auto gemm_slice = [&](const float* Wbase) {
      const float4* W4 = ((const float4*)Wbase) + jj;
      const float4* xh4 = (const float4*)xh;
#pragma unroll
      for (int d4 = 0; d4 < 32; ++d4) {
        float4 w0 = W4[(d4 * 4 + 0) * 16];
        float4 w1 = W4[(d4 * 4 + 1) * 16];
        float4 w2 = W4[(d4 * 4 + 2) * 16];
        float4 w3 = W4[(d4 * 4 + 3) * 16];
#pragma unroll
        for (int ch = 0; ch < CHUNKS; ++ch) {
          float4 xv = xh4[(ch * 16 + ccl) * 33 + d4];
          acc[ch][0] += xv.x * w0.x + xv.y * w1.x + xv.z * w2.x + xv.w * w3.x;
          acc[ch][1] += xv.x * w0.y + xv.y * w1.y + xv.z * w2.y + xv.w * w3.y;
          acc[ch][2] += xv.x * w0.z + xv.y * w1.z + xv.z * w2.z + xv.w * w3.z;
          acc[ch][3] += xv.x * w0.w + xv.y * w1.w + xv.z * w2.w + xv.w * w3.w;
        }
      }
    };

#pragma unroll
    for (int dsl = 0; dsl < NSLX; ++dsl) {
      __syncthreads();
#pragma unroll
      for (int ch = 0; ch < CHUNKS; ++ch) {
        const int q = q00 + (ch << 4) + scc;
        const float* src = X + ((size_t)t * BB + (q & 127)) * Din + (dsl << 7) + sd;
        *(float4*)&xh[(ch * 16 + scc) * 132 + sd] = *(const float4*)src;
        *(float4*)&xh[(ch * 16 + scc) * 132 + sd + 4] = *(const float4*)(src + 4);
      }
      __syncthreads();
      gemm_slice(Wl + (size_t)(dsl << 7) * 64);
    }

    if (s > 0) {
      if (tid == 0 && !dead) {
        const unsigned int target = 16u * (unsigned int)s;
        int spins = 0;
        for (;;) {
          unsigned int v = __hip_atomic_fetch_add(myctr, 0u, __ATOMIC_RELAXED,
                                                  __HIP_MEMORY_SCOPE_AGENT);
          if (v >= target) break;
          __builtin_amdgcn_s_sleep(2);
          if (++spins > (1 << 18)) { dead = true; break; }
        }
      }
      __syncthreads();
      __builtin_amdgcn_fence(__ATOMIC_ACQUIRE, "agent");
    }

#pragma unroll
    for (int dsl = 0; dsl < 2; ++dsl) {
      __syncthreads();
#pragma unroll
      for (int ch = 0; ch < CHUNKS; ++ch) {
        const int q = q00 + (ch << 4) + scc;
        const float* src = hread + (size_t)q * HH + (dsl << 7) + sd;
        *(float4*)&xh[(ch * 16 + scc) * 132 + sd] = *(const float4*)src;
        *(float4*)&xh[(ch * 16 + scc) * 132 + sd + 4] = *(const float4*)(src + 4);
      }
      __syncthreads();
      gemm_slice(Wl + (size_t)(Din + (dsl << 7)) * 64);
    }

#pragma unroll
    for (int ch = 0; ch < CHUNKS; ++ch) {
      const int q = q00 + (ch << 4) + ccl;
      const int b = q & 127;
      float gi = sigm(acc[ch][0] + bsum[0]);
      float gf = sigm(acc[ch][1] + bsum[1]);
      float gg = tanhf(acc[ch][2] + bsum[2]);
      float go = sigm(acc[ch][3] + bsum[3]);
      float c = gf * creg[ch] + gi * gg;
      creg[ch] = c;
      float h = go * tanhf(c);
      hwrite[(size_t)q * HH + unit] = h;
      Y[((size_t)t * BB + b) * HH + unit] = h;
    }

    __syncthreads();
    if (tid == 0)
      __hip_atomic_fetch_add(myctr, 1u, __ATOMIC_RELEASE,
                             __HIP_MEMORY_SCOPE_AGENT);
  }
}

__global__ void zero_out(float* p, size_t n) {
  size_t i = (size_t)blockIdx.x * blockDim.x + threadIdx.x;
  if (i < n) p[i] = 0.f;
}

template <int C16, int DinT>
static void launch_ks(dim3 grid, size_t lds, hipStream_t stream,
                      const float* X, float* Y, const float* Wih,
                      const float* Whh, const float* bih, const float* bhh,
                      float* hbuf, unsigned int* ctr, int n_steps, int rate,
                      size_t HB) {
  hipFuncSetAttribute(reinterpret_cast<const void*>(&lstm_layer_ks<C16, DinT>),
                      hipFuncAttributeMaxDynamicSharedMemorySize, (int)lds);
  lstm_layer_ks<C16, DinT><<<grid, dim3(256), lds, stream>>>(
      X, Y, Wih, Whh, bih, bhh, hbuf, ctr, n_steps, rate, HB);
}

template <int C, int N>
static void launch_layer(dim3 grid, size_t lds, hipStream_t stream,
                         const float* X, float* Y, const float* Wih,
                         const float* Whh, const float* bih, const float* bhh,
                         float* hbuf, unsigned int* ctr, int n_steps, int rate,
                         size_t HB) {
  hipFuncSetAttribute(reinterpret_cast<const void*>(&lstm_layer<C, N>),
                      hipFuncAttributeMaxDynamicSharedMemorySize, (int)lds);
  lstm_layer<C, N><<<grid, dim3(256), lds, stream>>>(
      X, Y, Wih, Whh, bih, bhh, hbuf, ctr, n_steps, rate, HB);
}

extern "C" void kernel_launch(void* const* d_in, const int* in_sizes, int n_in,
                              void* d_out, int out_size, void* d_ws, size_t ws_size,
                              hipStream_t stream) {
  const float* x = (const float*)d_in[0];
  const float* Wih0 = (const float*)d_in[1];
  const float* Whh0 = (const float*)d_in[2];
  const float* bih0 = (const float*)d_in[3];
  const float* bhh0 = (const float*)d_in[4];
  const float* Wih1 = (const float*)d_in[5];
  const float* Whh1 = (const float*)d_in[6];
  const float* bih1 = (const float*)d_in[7];
  const float* bhh1 = (const float*)d_in[8];
  const float* Wih2 = (const float*)d_in[9];
  const float* Whh2 = (const float*)d_in[10];
  const float* bih2 = (const float*)d_in[11];
  const float* bhh2 = (const float*)d_in[12];

  const size_t outElems = (size_t)TT * BB * HH; // 33,554,432
  const size_t hcBytes = (size_t)2 * 512 * HH * sizeof(float) + 16 * 128;
  const size_t needWs = outElems * sizeof(float) + hcBytes;

  if (ws_size < needWs) {
    zero_out<<<dim3((unsigned)((outElems + 255) / 256)), dim3(256), 0, stream>>>(
        (float*)d_out, outElems);
    return;
  }

  float* out0 = (float*)d_ws;
  float* hbuf = (float*)((char*)d_ws + outElems * sizeof(float));
  unsigned int* ctr =
      (unsigned int*)((char*)hbuf + (size_t)2 * 512 * HH * sizeof(float));
  float* dout = (float*)d_out;

  // LDS: ks kernel: Wl Dtot*32 + xh C16*264 floats; old kernel unchanged.
  const size_t ldsK0 = ((size_t)384 * 32 + 16 * 264) * sizeof(float);  // 66,048
  const size_t ldsK1 = ((size_t)512 * 32 + 32 * 264) * sizeof(float);  // 99,328
  const size_t lds12 = (512 * 64 + 32 * 132) * sizeof(float);          // 147,968

  // Layer 0: rate 1, Beff 128 -> 8 groups x 32 WGs = 256 (all CUs), C16=16
  hipMemsetAsync(hbuf, 0, hcBytes, stream);
  launch_ks<16, 128>(dim3(256), ldsK0, stream, x, out0, Wih0, Whh0, bih0, bhh0,
                     hbuf, ctr, 1024, 1, (size_t)128 * HH);

  // Layer 1: rate 2, Beff 256 -> 8 groups x 32 WGs = 256, C16=32
  hipMemsetAsync(hbuf, 0, hcBytes, stream);
  launch_ks<32, 256>(dim3(256), ldsK1, stream, out0, dout, Wih1, Whh1, bih1,
                     bhh1, hbuf, ctr, 512, 2, (size_t)256 * HH);

  // Layer 2: rate 4, Beff 512 -> 16 groups x 16 WGs = 256 (proven kernel)
  hipMemsetAsync(hbuf, 0, hcBytes, stream);
  launch_layer<2, 2>(dim3(256), lds12, stream, dout, out0, Wih2, Whh2, bih2,
                     bhh2, hbuf, ctr, 256, 4, (size_t)512 * HH);

  hipMemcpyAsync(d_out, out0, outElems * sizeof(float), hipMemcpyDeviceToDevice,
                 stream);
}

// Round 5
// 44988.232 us; speedup vs baseline: 33.6123x; 10.1646x over previous
//
#include <hip/hip_runtime.h>
#include <math.h>

#define TT 1024
#define BB 128
#define HH 256

__device__ __forceinline__ float sigm(float x) { return 1.0f / (1.0f + expf(-x)); }

// ---------------------------------------------------------------------------
// K-split persistent LSTM layer (all 3 layers now use this structure).
// 32 WGs per group, 8 hidden units per WG, 4-way K-split across threads with
// shfl_xor butterfly combine.
//   thread = ccl(3b) | kh(2b) | jj(3b):  jj = unit 0-7, kh = K quarter,
//   ccl = chain octant (CH_T = C16/8 chains per thread).
// LDS: Wl[Dtot][32] (gate-vector float4 per unit) + xh[C16][264] staging.
// Sync protocol (round-2 proven): RELAXED RMW poll, RELEASE fetch_add publish
// (one wbl2), one agent ACQUIRE fence in all waves after the poll.
// Round-4 evidence: this structure runs ~3-5us/step; the old 16-unit/WG
// structure showed a ~2.8 GB/step HBM traffic storm (725 GB/dispatch,
// VALUBusy 0.7%) - do not resurrect it.
// ---------------------------------------------------------------------------
template <int C16, int DinT>
__device__ __forceinline__ void lstm_ks_body(
    const float* __restrict__ X, float* __restrict__ Y,
    const float* __restrict__ Wih, const float* __restrict__ Whh,
    const float* __restrict__ bih, const float* __restrict__ bhh,
    float* __restrict__ hbuf, unsigned int* __restrict__ ctr,
    int n_steps, int rate, size_t HB) {
  constexpr int Dtot = DinT + HH;
  constexpr int CH_T = C16 / 8;       // chains per thread
  constexpr int PITCH = 264;          // xh row pitch in floats (66 f4)

  extern __shared__ float lds[];
  float* Wl = lds;                    // [Dtot][32]  (d slow; 32 = 8 units x 4 gates)
  float* xh = lds + Dtot * 32;        // [C16][264]

  const int tid = threadIdx.x;
  const int jj = tid & 7;             // unit within slice
  const int kh = (tid >> 3) & 3;      // K quarter
  const int ccl = tid >> 5;           // chain octant (0-7)
  const int group = blockIdx.x >> 5;  // 32 WGs per group
  const int slice = blockIdx.x & 31;
  const int unit = slice * 8 + jj;
  unsigned int* const myctr = ctr + (group << 5);

  // One-time: Wl[d][u*4+g] = fused weight row (gate-vector layout).
  for (int idx = tid; idx < Dtot * 32; idx += 256) {
    int d = idx >> 5, col = idx & 31;
    int grow = ((col & 3) << 8) + slice * 8 + (col >> 2); // gate*256 + unit
    Wl[idx] = (d < DinT) ? Wih[(size_t)grow * DinT + d]
                         : Whh[(size_t)grow * HH + (d - DinT)];
  }
  float bsum[4];
#pragma unroll
  for (int g = 0; g < 4; ++g)
    bsum[g] = bih[(g << 8) + unit] + bhh[(g << 8) + unit];

  float creg[CH_T];
#pragma unroll
  for (int c = 0; c < CH_T; ++c) creg[c] = 0.f;

  __syncthreads();

  const int q00 = group * C16;   // first global chain (C16-aligned; never
  const int toff = q00 >> 7;     // crosses a 128 boundary -> uniform toff)
  bool dead = false;

  float acc[CH_T][4];

  for (int s = 0; s < n_steps; ++s) {
    float* hwrite = hbuf + (size_t)(s & 1) * HB;
    const float* hread = hbuf + (size_t)((s & 1) ^ 1) * HB;
    const int t = s * rate + toff;

#pragma unroll
    for (int c = 0; c < CH_T; ++c)
#pragma unroll
      for (int g = 0; g < 4; ++g) acc[c][g] = 0.f;

    // GEMM over this thread's K-quarter of one staged operand block.
    // wb = Wl row offset (0 for x, DinT for h); NI = d4 iterations (Kq/4).
    auto gemm_q = [&](int wb, int ko, int ko4, int NI) {
      const float4* W4 = (const float4*)Wl;
      const float4* X4 = (const float4*)xh;
      for (int d4 = 0; d4 < NI; ++d4) {
        float4 w0 = W4[(wb + ko + d4 * 4 + 0) * 8 + jj];
        float4 w1 = W4[(wb + ko + d4 * 4 + 1) * 8 + jj];
        float4 w2 = W4[(wb + ko + d4 * 4 + 2) * 8 + jj];
        float4 w3 = W4[(wb + ko + d4 * 4 + 3) * 8 + jj];
#pragma unroll
        for (int c = 0; c < CH_T; ++c) {
          float4 xv = X4[(ccl * CH_T + c) * 66 + ko4 + d4];
          acc[c][0] += xv.x * w0.x + xv.y * w1.x + xv.z * w2.x + xv.w * w3.x;
          acc[c][1] += xv.x * w0.y + xv.y * w1.y + xv.z * w2.y + xv.w * w3.y;
          acc[c][2] += xv.x * w0.z + xv.y * w1.z + xv.z * w2.z + xv.w * w3.z;
          acc[c][3] += xv.x * w0.w + xv.y * w1.w + xv.z * w2.w + xv.w * w3.w;
        }
      }
    };

    // ---- x contribution (no cross-WG dependency; overlaps peers' publish) --
#pragma unroll
    for (int idx = tid; idx < C16 * (DinT / 4); idx += 256) {
      int r = idx / (DinT / 4), cl = idx % (DinT / 4);
      int q = q00 + r;
      *(float4*)&xh[r * PITCH + cl * 4] =
          *(const float4*)(X + ((size_t)t * BB + (q & 127)) * DinT + cl * 4);
    }
    __syncthreads();
    gemm_q(0, kh * (DinT / 4), kh * (DinT / 16), DinT / 16);

    // ---- wait until all 32 WGs of the group published h(s-1) ----
    if (s > 0) {
      if (tid == 0 && !dead) {
        const unsigned int target = 32u * (unsigned int)s;
        int spins = 0;
        for (;;) {
          unsigned int v = __hip_atomic_fetch_add(myctr, 0u, __ATOMIC_RELAXED,
                                                  __HIP_MEMORY_SCOPE_AGENT);
          if (v >= target) break;
          __builtin_amdgcn_s_sleep(2);
          if (++spins > (1 << 18)) { dead = true; break; }
        }
      }
      __syncthreads();  // also guards xh reuse (gemm_x done in all threads)
      __builtin_amdgcn_fence(__ATOMIC_ACQUIRE, "agent");
    } else {
      __syncthreads();
    }

    // ---- h contribution: stage all C16 x 256, one sync, gemm kh quarter ----
#pragma unroll
    for (int idx = tid; idx < C16 * 64; idx += 256) {
      int r = idx >> 6, cl = idx & 63;
      int q = q00 + r;
      *(float4*)&xh[r * PITCH + cl * 4] =
          *(const float4*)(hread + (size_t)q * HH + cl * 4);
    }
    __syncthreads();
    gemm_q(DinT, kh * 64, kh * 16, 16);

    // ---- butterfly combine across the 4 kh replicas (lane bits 3,4) ----
#pragma unroll
    for (int c = 0; c < CH_T; ++c)
#pragma unroll
      for (int g = 0; g < 4; ++g) {
        float v = acc[c][g];
        v += __shfl_xor(v, 8);
        v += __shfl_xor(v, 16);
        acc[c][g] = v;
      }

    // ---- LSTM pointwise (all kh replicas, identical); stores kh==0 only ----
#pragma unroll
    for (int c = 0; c < CH_T; ++c) {
      const int q = q00 + ccl * CH_T + c;
      const int b = q & 127;
      float gi = sigm(acc[c][0] + bsum[0]);
      float gf = sigm(acc[c][1] + bsum[1]);
      float gg = tanhf(acc[c][2] + bsum[2]);
      float go = sigm(acc[c][3] + bsum[3]);
      float cc = gf * creg[c] + gi * gg;
      creg[c] = cc;
      float h = go * tanhf(cc);
      if (kh == 0) {
        hwrite[(size_t)q * HH + unit] = h;
        Y[((size_t)t * BB + b) * HH + unit] = h;
      }
    }

    // ---- publish: sync drains vmcnt; RELEASE RMW does one wbl2 + bump ----
    __syncthreads();
    if (tid == 0)
      __hip_atomic_fetch_add(myctr, 1u, __ATOMIC_RELEASE,
                             __HIP_MEMORY_SCOPE_AGENT);
  }
}

// Distinctly-named wrappers so rocprof attributes per-layer unambiguously.
__global__ __launch_bounds__(256, 1) void lstm_ks_L0(
    const float* __restrict__ X, float* __restrict__ Y,
    const float* __restrict__ Wih, const float* __restrict__ Whh,
    const float* __restrict__ bih, const float* __restrict__ bhh,
    float* __restrict__ hbuf, unsigned int* __restrict__ ctr,
    int n_steps, int rate, size_t HB) {
  lstm_ks_body<16, 128>(X, Y, Wih, Whh, bih, bhh, hbuf, ctr, n_steps, rate, HB);
}
__global__ __launch_bounds__(256, 1) void lstm_ks_L1(
    const float* __restrict__ X, float* __restrict__ Y,
    const float* __restrict__ Wih, const float* __restrict__ Whh,
    const float* __restrict__ bih, const float* __restrict__ bhh,
    float* __restrict__ hbuf, unsigned int* __restrict__ ctr,
    int n_steps, int rate, size_t HB) {
  lstm_ks_body<32, 256>(X, Y, Wih, Whh, bih, bhh, hbuf, ctr, n_steps, rate, HB);
}
__global__ __launch_bounds__(256, 1) void lstm_ks_L2(
    const float* __restrict__ X, float* __restrict__ Y,
    const float* __restrict__ Wih, const float* __restrict__ Whh,
    const float* __restrict__ bih, const float* __restrict__ bhh,
    float* __restrict__ hbuf, unsigned int* __restrict__ ctr,
    int n_steps, int rate, size_t HB) {
  lstm_ks_body<64, 256>(X, Y, Wih, Whh, bih, bhh, hbuf, ctr, n_steps, rate, HB);
}

__global__ void zero_out(float* p, size_t n) {
  size_t i = (size_t)blockIdx.x * blockDim.x + threadIdx.x;
  if (i < n) p[i] = 0.f;
}

extern "C" void kernel_launch(void* const* d_in, const int* in_sizes, int n_in,
                              void* d_out, int out_size, void* d_ws, size_t ws_size,
                              hipStream_t stream) {
  const float* x = (const float*)d_in[0];
  const float* Wih0 = (const float*)d_in[1];
  const float* Whh0 = (const float*)d_in[2];
  const float* bih0 = (const float*)d_in[3];
  const float* bhh0 = (const float*)d_in[4];
  const float* Wih1 = (const float*)d_in[5];
  const float* Whh1 = (const float*)d_in[6];
  const float* bih1 = (const float*)d_in[7];
  const float* bhh1 = (const float*)d_in[8];
  const float* Wih2 = (const float*)d_in[9];
  const float* Whh2 = (const float*)d_in[10];
  const float* bih2 = (const float*)d_in[11];
  const float* bhh2 = (const float*)d_in[12];

  const size_t outElems = (size_t)TT * BB * HH; // 33,554,432
  const size_t hcBytes = (size_t)2 * 512 * HH * sizeof(float) + 16 * 128;
  const size_t needWs = outElems * sizeof(float) + hcBytes;

  // Workspace guard: convert a potential OOB-write container-kill into a
  // clean verification failure (diagnostic signal, never a crash).
  if (ws_size < needWs) {
    zero_out<<<dim3((unsigned)((outElems + 255) / 256)), dim3(256), 0, stream>>>(
        (float*)d_out, outElems);
    return;
  }

  float* out0 = (float*)d_ws;
  float* hbuf = (float*)((char*)d_ws + outElems * sizeof(float));
  unsigned int* ctr =
      (unsigned int*)((char*)hbuf + (size_t)2 * 512 * HH * sizeof(float));
  float* dout = (float*)d_out;

  // LDS: Wl = Dtot*32 floats + xh = C16*264 floats.
  const size_t ldsK0 = ((size_t)384 * 32 + 16 * 264) * sizeof(float);  //  66,048
  const size_t ldsK1 = ((size_t)512 * 32 + 32 * 264) * sizeof(float);  //  99,328
  const size_t ldsK2 = ((size_t)512 * 32 + 64 * 264) * sizeof(float);  // 133,120

  // Layer 0: rate 1, Beff 128 -> 8 groups x 32 WGs = 256, C16=16
  hipFuncSetAttribute(reinterpret_cast<const void*>(&lstm_ks_L0),
                      hipFuncAttributeMaxDynamicSharedMemorySize, (int)ldsK0);
  hipMemsetAsync(hbuf, 0, hcBytes, stream);
  lstm_ks_L0<<<dim3(256), dim3(256), ldsK0, stream>>>(
      x, out0, Wih0, Whh0, bih0, bhh0, hbuf, ctr, 1024, 1, (size_t)128 * HH);

  // Layer 1: rate 2, Beff 256 -> 8 groups x 32 WGs = 256, C16=32
  hipFuncSetAttribute(reinterpret_cast<const void*>(&lstm_ks_L1),
                      hipFuncAttributeMaxDynamicSharedMemorySize, (int)ldsK1);
  hipMemsetAsync(hbuf, 0, hcBytes, stream);
  lstm_ks_L1<<<dim3(256), dim3(256), ldsK1, stream>>>(
      out0, dout, Wih1, Whh1, bih1, bhh1, hbuf, ctr, 512, 2, (size_t)256 * HH);

  // Layer 2: rate 4, Beff 512 -> 8 groups x 32 WGs = 256, C16=64
  hipFuncSetAttribute(reinterpret_cast<const void*>(&lstm_ks_L2),
                      hipFuncAttributeMaxDynamicSharedMemorySize, (int)ldsK2);
  hipMemsetAsync(hbuf, 0, hcBytes, stream);
  lstm_ks_L2<<<dim3(256), dim3(256), ldsK2, stream>>>(
      dout, out0, Wih2, Whh2, bih2, bhh2, hbuf, ctr, 256, 4, (size_t)512 * HH);

  // final result back to d_out
  hipMemcpyAsync(d_out, out0, outElems * sizeof(float), hipMemcpyDeviceToDevice,
                 stream);
}